// Round 10
// baseline (213.901 us; speedup 1.0000x reference)
//
#include <hip/hip_runtime.h>
#include <hip/hip_bf16.h>
#include <stdint.h>

typedef __attribute__((ext_vector_type(8))) short bf16x8;   // 8 bf16 = 4 VGPR
typedef __attribute__((ext_vector_type(4))) float f32x4;
typedef __attribute__((ext_vector_type(16))) float f32x16;  // 32x32 MFMA C/D
typedef __attribute__((ext_vector_type(2))) unsigned int u32x2;
typedef unsigned short u16;

#define DEVI static __device__ __forceinline__

DEVI u16 f2bf(float f) {  // RNE fp32 -> bf16
  union { float f; uint32_t u; } x; x.f = f;
  uint32_t r = (x.u + 0x7FFFu + ((x.u >> 16) & 1u)) >> 16;
  return (u16)r;
}

DEVI void gload_lds16(const void* g, void* lds) {
  __builtin_amdgcn_global_load_lds(
      (const __attribute__((address_space(1))) void*)(void*)g,
      (__attribute__((address_space(3))) void*)lds, 16, 0, 0);
}

// low 32 bits of a flat shared-pointer = LDS byte offset
DEVI unsigned ldsaddr(const void* p) { return (unsigned)(uintptr_t)p; }

// ---------------- fused fp32->bf16 converts + bias copies (1 dispatch) ----------------
__global__ void cvt_all_kernel(const float* __restrict__ x,
                               const float* __restrict__ Wq, const float* __restrict__ Wk,
                               const float* __restrict__ Wv, const float* __restrict__ Wo,
                               const float* __restrict__ bq, const float* __restrict__ bk,
                               const float* __restrict__ bv,
                               u16* __restrict__ xb, u16* __restrict__ Wqkvb,
                               u16* __restrict__ Wob, float* __restrict__ bqkv) {
  const int X4 = 2097152;          // x in float4 units (8192*1024/4)
  const int W4 = 262144;           // per-W float4 units (2^18)
  const int total = X4 + 4 * W4 + 768;
  int i = blockIdx.x * blockDim.x + threadIdx.x;
  const int stride = gridDim.x * blockDim.x;
  for (; i < total; i += stride) {
    if (i < X4) {
      float4 v = ((const float4*)x)[i];
      ((ushort4*)xb)[i] = make_ushort4(f2bf(v.x), f2bf(v.y), f2bf(v.z), f2bf(v.w));
    } else if (i < X4 + 4 * W4) {
      int j = i - X4;
      int which = j >> 18;
      int o = j & (W4 - 1);
      const float* src = which == 0 ? Wq : which == 1 ? Wk : which == 2 ? Wv : Wo;
      u16* dst = (which == 3) ? Wob : (Wqkvb + (size_t)which * 1048576);
      float4 v = ((const float4*)src)[o];
      ((ushort4*)dst)[o] = make_ushort4(f2bf(v.x), f2bf(v.y), f2bf(v.z), f2bf(v.w));
    } else {
      int j = i - X4 - 4 * W4;     // 0..767
      int which = j >> 8;
      int o = j & 255;
      const float* src = which == 0 ? bq : which == 1 ? bk : bv;
      ((float4*)bqkv)[which * 256 + o] = ((const float4*)src)[o];
    }
  }
}

// ---------------- GEMM: 128x256 tile, BK=64, 8 waves, 4-phase interleave ----------------
// C[M,N] = A[M,K] @ B[N,K]^T + bias (+col scale). T2 XOR-swizzled LDS via pre-swizzled
// global_load_lds sources; counted-stage double buffer; setprio around MFMA clusters.
// LDS phys layout: tile[row][64] bf16, phys_chunk = logical_chunk ^ (row&7) (16B chunks).
template<int OUT_BF16>
__global__ __launch_bounds__(512, 2)
void gemm_bt8_kernel(const u16* __restrict__ A, const u16* __restrict__ B,
                     const float* __restrict__ bias, void* __restrict__ C,
                     int M, int N, int K, int scale_cols, float scale_val) {
  __shared__ u16 As[2][8192];    // [buf][128 rows][64]  16 KB/buf
  __shared__ u16 Bs[2][16384];   // [buf][256 rows][64]  32 KB/buf
  const int tid = threadIdx.x;
  const int l = tid & 63;
  const int w = tid >> 6;
  const int wm = w >> 2, wn = w & 3;         // wave tile: 64(M) x 64(N)
  const int bn = blockIdx.x, bm = blockIdx.y;

  // --- staging sources: thread T covers LDS row trow=T>>3, phys chunk T&7;
  //     source column chunk = phys ^ (row&7)  (pre-swizzle, rule 21)
  const int trow = tid >> 3;
  const int lc = (tid & 7) ^ (trow & 7);
  const u16* gA0 = A + (size_t)(bm * 128 + trow) * K + lc * 8;
  const u16* gA1 = gA0 + (size_t)64 * K;
  const u16* gB0 = B + (size_t)(bn * 256 + trow) * K + lc * 8;
  const u16* gB1 = gB0 + (size_t)64 * K;
  const u16* gB2 = gB0 + (size_t)128 * K;
  const u16* gB3 = gB0 + (size_t)192 * K;

#define GSTAGE(d, kt) { \
    const size_t ko = (size_t)(kt) * 64; \
    gload_lds16(gA0 + ko, &As[d][tid * 8]); \
    gload_lds16(gA1 + ko, &As[d][4096 + tid * 8]); \
    gload_lds16(gB0 + ko, &Bs[d][tid * 8]); \
    gload_lds16(gB1 + ko, &Bs[d][4096 + tid * 8]); \
    gload_lds16(gB2 + ko, &Bs[d][8192 + tid * 8]); \
    gload_lds16(gB3 + ko, &Bs[d][12288 + tid * 8]); \
  }

  // --- frag read offsets (u16 units): row*64 + (q ^ (l&7))*8, q = kk*4 + (l>>4)
  const int arow = (wm * 64 + (l & 15)) * 64;
  const int brow = (wn * 64 + (l & 15)) * 64;
  int coff[2];
#pragma unroll
  for (int kk = 0; kk < 2; ++kk) coff[kk] = (((kk * 4 + (l >> 4)) ^ (l & 7)) * 8);

  f32x4 acc[4][4] = {};
  const int NT = K >> 6;   // K-tiles of 64

  GSTAGE(0, 0);

  for (int kt = 0; kt < NT; ++kt) {
    const int cur = kt & 1;
    asm volatile("s_waitcnt vmcnt(0)" ::: "memory");   // own tile-kt loads landed
    __builtin_amdgcn_s_barrier();                      // all waves' loads in; buf^1 free
    asm volatile("" ::: "memory");
    if (kt < NT - 1) GSTAGE(cur ^ 1, kt + 1);          // full-tile-lead prefetch

    const u16* ap = &As[cur][0];
    const u16* bp = &Bs[cur][0];

    // ---- phase 0: all B-frags (held in regs) + A[m0]; 8 MFMA
    bf16x8 bf[4][2], af[2];
#pragma unroll
    for (int nf = 0; nf < 4; ++nf)
#pragma unroll
      for (int kk = 0; kk < 2; ++kk)
        bf[nf][kk] = *(const bf16x8*)&bp[brow + nf * 1024 + coff[kk]];
#pragma unroll
    for (int kk = 0; kk < 2; ++kk) af[kk] = *(const bf16x8*)&ap[arow + coff[kk]];
    asm volatile("s_waitcnt lgkmcnt(0)" ::: "memory");
    __builtin_amdgcn_sched_barrier(0);                 // rule 18
    __builtin_amdgcn_s_setprio(1);
#pragma unroll
    for (int kk = 0; kk < 2; ++kk)
#pragma unroll
      for (int nf = 0; nf < 4; ++nf)
        acc[0][nf] = __builtin_amdgcn_mfma_f32_16x16x32_bf16(af[kk], bf[nf][kk], acc[0][nf], 0, 0, 0);
    __builtin_amdgcn_s_setprio(0);
    __builtin_amdgcn_s_barrier();

    // ---- phases 1..3: A[m_p] + 8 MFMA each
#pragma unroll
    for (int mf = 1; mf < 4; ++mf) {
#pragma unroll
      for (int kk = 0; kk < 2; ++kk)
        af[kk] = *(const bf16x8*)&ap[arow + mf * 1024 + coff[kk]];
      asm volatile("s_waitcnt lgkmcnt(0)" ::: "memory");
      __builtin_amdgcn_sched_barrier(0);
      __builtin_amdgcn_s_setprio(1);
#pragma unroll
      for (int kk = 0; kk < 2; ++kk)
#pragma unroll
        for (int nf = 0; nf < 4; ++nf)
          acc[mf][nf] = __builtin_amdgcn_mfma_f32_16x16x32_bf16(af[kk], bf[nf][kk], acc[mf][nf], 0, 0, 0);
      __builtin_amdgcn_s_setprio(0);
      if (mf < 3) __builtin_amdgcn_s_barrier();   // p3's end handled by next tile's top barrier
    }
    asm volatile("" ::: "memory");
  }

  // ---- epilogue (C/D layout m89-verified: col = l&15, row = (l>>4)*4 + j)
  const int rbase = bm * 128 + wm * 64 + (l >> 4) * 4;
  const int cbase = bn * 256 + wn * 64 + (l & 15);
#pragma unroll
  for (int nf = 0; nf < 4; ++nf) {
    int col = cbase + nf * 16;
    float bsv = bias[col];
    float sc = (col < scale_cols) ? scale_val : 1.0f;
#pragma unroll
    for (int mf = 0; mf < 4; ++mf) {
#pragma unroll
      for (int j = 0; j < 4; ++j) {
        int row = rbase + mf * 16 + j;
        float v = (acc[mf][nf][j] + bsv) * sc;
        if (OUT_BF16) ((u16*)C)[(size_t)row * N + col] = f2bf(v);
        else          ((float*)C)[(size_t)row * N + col] = v;
      }
    }
  }
#undef GSTAGE
}

// softmax + P->bf16 A-frag build for one group: exp2 in place, lane-local rowsum,
// cvt_pk pairs + single symmetric cross-half exchange (lane c <-> c+32).
DEVI void softmax_pa(f32x16& sA, f32x16& sB, bf16x8* pa, float& lsum, int hi) {
  float rs = 0.f;
#pragma unroll
  for (int r = 0; r < 16; ++r) { sA[r] = __builtin_amdgcn_exp2f(sA[r]); rs += sA[r]; }
#pragma unroll
  for (int r = 0; r < 16; ++r) { sB[r] = __builtin_amdgcn_exp2f(sB[r]); rs += sB[r]; }
  lsum += rs + __shfl_xor(rs, 32, 64);
#pragma unroll
  for (int i = 0; i < 4; ++i) {
    float p0 = (8 * i + 0 < 16) ? sA[(8 * i + 0) & 15] : sB[(8 * i + 0) & 15];
    float p1 = (8 * i + 1 < 16) ? sA[(8 * i + 1) & 15] : sB[(8 * i + 1) & 15];
    float p2 = (8 * i + 2 < 16) ? sA[(8 * i + 2) & 15] : sB[(8 * i + 2) & 15];
    float p3 = (8 * i + 3 < 16) ? sA[(8 * i + 3) & 15] : sB[(8 * i + 3) & 15];
    float p4 = (8 * i + 4 < 16) ? sA[(8 * i + 4) & 15] : sB[(8 * i + 4) & 15];
    float p5 = (8 * i + 5 < 16) ? sA[(8 * i + 5) & 15] : sB[(8 * i + 5) & 15];
    float p6 = (8 * i + 6 < 16) ? sA[(8 * i + 6) & 15] : sB[(8 * i + 6) & 15];
    float p7 = (8 * i + 7 < 16) ? sA[(8 * i + 7) & 15] : sB[(8 * i + 7) & 15];
    unsigned a0, a1, b0, b1;
    asm("v_cvt_pk_bf16_f32 %0, %1, %2" : "=v"(a0) : "v"(p0), "v"(p1));
    asm("v_cvt_pk_bf16_f32 %0, %1, %2" : "=v"(a1) : "v"(p2), "v"(p3));
    asm("v_cvt_pk_bf16_f32 %0, %1, %2" : "=v"(b0) : "v"(p4), "v"(p5));
    asm("v_cvt_pk_bf16_f32 %0, %1, %2" : "=v"(b1) : "v"(p6), "v"(p7));
    unsigned t0 = hi ? a0 : b0;   // each lane sends the pair its partner needs
    unsigned t1 = hi ? a1 : b1;
    unsigned x0 = (unsigned)__shfl_xor((int)t0, 32, 64);
    unsigned x1 = (unsigned)__shfl_xor((int)t1, 32, 64);
    union { unsigned u[4]; bf16x8 v; } U;
    U.u[0] = hi ? x0 : a0;   // keys base+0,1
    U.u[1] = hi ? x1 : a1;   // keys base+2,3
    U.u[2] = hi ? b0 : x0;   // keys base+4,5
    U.u[3] = hi ? b1 : x1;   // keys base+6,7
    pa[i] = U.v;
  }
}

// ---------------- flash attention (R8 version — best measured: 92.6 us) ----------------
// Swapped-QK^T 32x32, max-free, 64 q-rows/wave, depth-2 counted prefetch, 3 buffers.
__global__ __launch_bounds__(256, 2)
void attn_kernel(const u16* __restrict__ QKV, u16* __restrict__ O) {
  __shared__ u16 Ks[3][4096];  // [buf][64 key][64 d], blk-swizzled: phys = db ^ (key&7)
  __shared__ u16 Vs[3][4096];  // [buf] subtiled [key>>2][d>>4][key&3][d&15] for tr_b16

  const int tid = threadIdx.x;
  const int l = tid & 63, w = tid >> 6;
  const int hi = l >> 5, c = l & 31;
  const int bh = blockIdx.y, b = bh >> 4, h = bh & 15;
  const int qb = blockIdx.x * 256 + w * 64;   // 64 q-rows per wave
  const size_t rowbase = (size_t)b * 2048;

  bf16x8 qf0[4], qf1[4];
  {
    const u16* Qp0 = QKV + (rowbase + qb + c) * 3072 + h * 64 + hi * 8;
    const u16* Qp1 = QKV + (rowbase + qb + 32 + c) * 3072 + h * 64 + hi * 8;
#pragma unroll
    for (int kk = 0; kk < 4; ++kk) {
      qf0[kk] = *(const bf16x8*)(Qp0 + kk * 16);
      qf1[kk] = *(const bf16x8*)(Qp1 + kk * 16);
    }
  }

  const int kd0 = (w * 2 + 0) * 64 + l;
  const int kd1 = (w * 2 + 1) * 64 + l;
  const int rK0 = kd0 >> 3, dbK0 = (kd0 & 7) ^ (rK0 & 7);
  const int rK1 = kd1 >> 3, dbK1 = (kd1 & 7) ^ (rK1 & 7);
  const u16* srcK0 = QKV + (rowbase + rK0) * 3072 + 1024 + h * 64 + dbK0 * 8;
  const u16* srcK1 = QKV + (rowbase + rK1) * 3072 + 1024 + h * 64 + dbK1 * 8;
  const int kV0 = (kd0 >> 5) * 4 + ((kd0 >> 1) & 3), dV0 = ((kd0 >> 3) & 3) * 16 + (kd0 & 1) * 8;
  const int kV1 = (kd1 >> 5) * 4 + ((kd1 >> 1) & 3), dV1 = ((kd1 >> 3) & 3) * 16 + (kd1 & 1) * 8;
  const u16* srcV0 = QKV + (rowbase + kV0) * 3072 + 2048 + h * 64 + dV0;
  const u16* srcV1 = QKV + (rowbase + kV1) * 3072 + 2048 + h * 64 + dV1;

#define STAGE(buf, tile) { \
    const size_t koff = (size_t)(tile) * 64 * 3072; \
    gload_lds16(srcK0 + koff, &Ks[buf][(w * 2 + 0) * 512]); \
    gload_lds16(srcK1 + koff, &Ks[buf][(w * 2 + 1) * 512]); \
    gload_lds16(srcV0 + koff, &Vs[buf][(w * 2 + 0) * 512]); \
    gload_lds16(srcV1 + koff, &Vs[buf][(w * 2 + 1) * 512]); \
  }

  int koffs[4];
#pragma unroll
  for (int kk = 0; kk < 4; ++kk) koffs[kk] = (((kk * 2 + hi) ^ (c & 7)) * 8);
  const int kbase = c * 64;

  const unsigned vbase = ldsaddr(&Vs[0][0]) + (unsigned)(hi * 1024 + (c >> 4) * 128 + (c & 15) * 8);

  f32x16 o00 = {0,0,0,0,0,0,0,0,0,0,0,0,0,0,0,0};
  f32x16 o01 = {0,0,0,0,0,0,0,0,0,0,0,0,0,0,0,0};
  f32x16 o10 = {0,0,0,0,0,0,0,0,0,0,0,0,0,0,0,0};
  f32x16 o11 = {0,0,0,0,0,0,0,0,0,0,0,0,0,0,0,0};
  float lsum0 = 0.f, lsum1 = 0.f;

  STAGE(0, 0);
  STAGE(1, 1);

  int cur = 0;
  for (int t = 0; t < 32; ++t) {
    if (t < 31) { asm volatile("s_waitcnt vmcnt(4)" ::: "memory"); }
    else        { asm volatile("s_waitcnt vmcnt(0)" ::: "memory"); }
    __builtin_amdgcn_s_barrier();
    asm volatile("" ::: "memory");

    if (t < 30) {
      int bs = cur + 2; if (bs >= 3) bs -= 3;
      STAGE(bs, t + 2);
    }

    const u16* kp = &Ks[cur][0];
    bf16x8 kf[2][4];
#pragma unroll
    for (int kb = 0; kb < 2; ++kb)
#pragma unroll
      for (int kk = 0; kk < 4; ++kk)
        kf[kb][kk] = *(const bf16x8*)&kp[kbase + kb * 2048 + koffs[kk]];

    f32x16 sA0 = {0,0,0,0,0,0,0,0,0,0,0,0,0,0,0,0};
    f32x16 sB0 = {0,0,0,0,0,0,0,0,0,0,0,0,0,0,0,0};
    f32x16 sA1 = {0,0,0,0,0,0,0,0,0,0,0,0,0,0,0,0};
    f32x16 sB1 = {0,0,0,0,0,0,0,0,0,0,0,0,0,0,0,0};
#pragma unroll
    for (int kk = 0; kk < 4; ++kk) {
      sA0 = __builtin_amdgcn_mfma_f32_32x32x16_bf16(kf[0][kk], qf0[kk], sA0, 0, 0, 0);
      sB0 = __builtin_amdgcn_mfma_f32_32x32x16_bf16(kf[1][kk], qf0[kk], sB0, 0, 0, 0);
      sA1 = __builtin_amdgcn_mfma_f32_32x32x16_bf16(kf[0][kk], qf1[kk], sA1, 0, 0, 0);
      sB1 = __builtin_amdgcn_mfma_f32_32x32x16_bf16(kf[1][kk], qf1[kk], sB1, 0, 0, 0);
    }

    const unsigned va = vbase + (unsigned)(cur * 8192);
    u32x2 tt[4][4];
#pragma unroll
    for (int ks = 0; ks < 4; ++ks) {
      unsigned va_ks = va + (unsigned)(ks * 2048);
      asm volatile("ds_read_b64_tr_b16 %0, %1 offset:0"   : "=v"(tt[ks][0]) : "v"(va_ks));
      asm volatile("ds_read_b64_tr_b16 %0, %1 offset:512" : "=v"(tt[ks][1]) : "v"(va_ks));
      asm volatile("ds_read_b64_tr_b16 %0, %1 offset:256" : "=v"(tt[ks][2]) : "v"(va_ks));
      asm volatile("ds_read_b64_tr_b16 %0, %1 offset:768" : "=v"(tt[ks][3]) : "v"(va_ks));
    }

    bf16x8 pa0[4];
    softmax_pa(sA0, sB0, pa0, lsum0, hi);

    asm volatile("s_waitcnt lgkmcnt(0)" ::: "memory");
    __builtin_amdgcn_sched_barrier(0);

#pragma unroll
    for (int ks = 0; ks < 4; ++ks) {
      union { u32x2 d2[2]; bf16x8 v; } V0, V1;
      V0.d2[0] = tt[ks][0]; V0.d2[1] = tt[ks][1];
      V1.d2[0] = tt[ks][2]; V1.d2[1] = tt[ks][3];
      o00 = __builtin_amdgcn_mfma_f32_32x32x16_bf16(pa0[ks], V0.v, o00, 0, 0, 0);
      o01 = __builtin_amdgcn_mfma_f32_32x32x16_bf16(pa0[ks], V1.v, o01, 0, 0, 0);
    }

    bf16x8 pa1[4];
    softmax_pa(sA1, sB1, pa1, lsum1, hi);

#pragma unroll
    for (int ks = 0; ks < 4; ++ks) {
      union { u32x2 d2[2]; bf16x8 v; } V0, V1;
      V0.d2[0] = tt[ks][0]; V0.d2[1] = tt[ks][1];
      V1.d2[0] = tt[ks][2]; V1.d2[1] = tt[ks][3];
      o10 = __builtin_amdgcn_mfma_f32_32x32x16_bf16(pa1[ks], V0.v, o10, 0, 0, 0);
      o11 = __builtin_amdgcn_mfma_f32_32x32x16_bf16(pa1[ks], V1.v, o11, 0, 0, 0);
    }

    asm volatile("" ::: "memory");
    cur = (cur == 2) ? 0 : cur + 1;
  }

  u16* Op0 = O + (rowbase + qb) * 1024 + h * 64 + c;
  u16* Op1 = O + (rowbase + qb + 32) * 1024 + h * 64 + c;
#pragma unroll
  for (int r = 0; r < 16; ++r) {
    int q = (r & 3) + 8 * (r >> 2) + 4 * hi;
    float inv0 = 1.0f / __shfl(lsum0, q, 64);
    float inv1 = 1.0f / __shfl(lsum1, q, 64);
    Op0[(size_t)q * 1024]      = f2bf(o00[r] * inv0);
    Op0[(size_t)q * 1024 + 32] = f2bf(o01[r] * inv0);
    Op1[(size_t)q * 1024]      = f2bf(o10[r] * inv1);
    Op1[(size_t)q * 1024 + 32] = f2bf(o11[r] * inv1);
  }
#undef STAGE
}

extern "C" void kernel_launch(void* const* d_in, const int* in_sizes, int n_in,
                              void* d_out, int out_size, void* d_ws, size_t ws_size,
                              hipStream_t stream) {
  const float* x  = (const float*)d_in[0];
  const float* Wq = (const float*)d_in[1];
  const float* bq = (const float*)d_in[2];
  const float* Wk = (const float*)d_in[3];
  const float* bk = (const float*)d_in[4];
  const float* Wv = (const float*)d_in[5];
  const float* bv = (const float*)d_in[6];
  const float* Wo = (const float*)d_in[7];
  const float* bo = (const float*)d_in[8];
  float* out = (float*)d_out;

  char* ws = (char*)d_ws;
  u16*   xb    = (u16*)(ws);                  // 8192x1024 bf16
  u16*   Wqkvb = (u16*)(ws + 16777216);       // 3072x1024 bf16
  u16*   Wob   = (u16*)(ws + 23068672);       // 1024x1024 bf16
  float* bqkv  = (float*)(ws + 25165824);     // 3072 fp32
  u16*   QKV   = (u16*)(ws + 25178112);       // 8192x3072 bf16
  u16*   Oa    = (u16*)(ws + 75509760);       // 8192x1024 bf16

  cvt_all_kernel<<<2048, 256, 0, stream>>>(x, Wq, Wk, Wv, Wo, bq, bk, bv,
                                           xb, Wqkvb, Wob, bqkv);

  // QKV = x @ [Wq;Wk;Wv]^T + bias; Q cols scaled by log2e/8 (exp2-domain scores)
  gemm_bt8_kernel<1><<<dim3(12, 64), 512, 0, stream>>>(xb, Wqkvb, bqkv, QKV,
                                                       8192, 3072, 1024, 1024,
                                                       0.125f * 1.4426950408889634f);
  // flash attention (R8 best: swapped-QK^T 32x32, max-free, depth-2 counted prefetch)
  attn_kernel<<<dim3(8, 64), 256, 0, stream>>>(QKV, Oa);
  // out = Oa @ Wo^T + bo
  gemm_bt8_kernel<0><<<dim3(4, 64), 512, 0, stream>>>(Oa, Wob, bo, out,
                                                      8192, 1024, 1024, 0, 1.0f);
}

// Round 12
// 209.900 us; speedup vs baseline: 1.0191x; 1.0191x over previous
//
#include <hip/hip_runtime.h>
#include <hip/hip_bf16.h>
#include <stdint.h>

typedef __attribute__((ext_vector_type(8))) short bf16x8;   // 8 bf16 = 4 VGPR
typedef __attribute__((ext_vector_type(4))) float f32x4;
typedef __attribute__((ext_vector_type(16))) float f32x16;  // 32x32 MFMA C/D
typedef __attribute__((ext_vector_type(2))) unsigned int u32x2;
typedef unsigned short u16;

#define DEVI static __device__ __forceinline__

DEVI u16 f2bf(float f) {  // RNE fp32 -> bf16
  union { float f; uint32_t u; } x; x.f = f;
  uint32_t r = (x.u + 0x7FFFu + ((x.u >> 16) & 1u)) >> 16;
  return (u16)r;
}

DEVI float bf2f(u16 v) {
  union { uint32_t u; float f; } x; x.u = ((uint32_t)v) << 16; return x.f;
}

DEVI void gload_lds16(const void* g, void* lds) {
  __builtin_amdgcn_global_load_lds(
      (const __attribute__((address_space(1))) void*)(void*)g,
      (__attribute__((address_space(3))) void*)lds, 16, 0, 0);
}

// low 32 bits of a flat shared-pointer = LDS byte offset
DEVI unsigned ldsaddr(const void* p) { return (unsigned)(uintptr_t)p; }

// ---------------- fused fp32->bf16 converts + bias copies (1 dispatch) ----------------
__global__ void cvt_all_kernel(const float* __restrict__ x,
                               const float* __restrict__ Wq, const float* __restrict__ Wk,
                               const float* __restrict__ Wv, const float* __restrict__ Wo,
                               const float* __restrict__ bq, const float* __restrict__ bk,
                               const float* __restrict__ bv,
                               u16* __restrict__ xb, u16* __restrict__ Wqkvb,
                               u16* __restrict__ Wob, float* __restrict__ bqkv) {
  const int X4 = 2097152;          // x in float4 units (8192*1024/4)
  const int W4 = 262144;           // per-W float4 units (2^18)
  const int total = X4 + 4 * W4 + 768;
  int i = blockIdx.x * blockDim.x + threadIdx.x;
  const int stride = gridDim.x * blockDim.x;
  for (; i < total; i += stride) {
    if (i < X4) {
      float4 v = ((const float4*)x)[i];
      ((ushort4*)xb)[i] = make_ushort4(f2bf(v.x), f2bf(v.y), f2bf(v.z), f2bf(v.w));
    } else if (i < X4 + 4 * W4) {
      int j = i - X4;
      int which = j >> 18;
      int o = j & (W4 - 1);
      const float* src = which == 0 ? Wq : which == 1 ? Wk : which == 2 ? Wv : Wo;
      u16* dst = (which == 3) ? Wob : (Wqkvb + (size_t)which * 1048576);
      float4 v = ((const float4*)src)[o];
      ((ushort4*)dst)[o] = make_ushort4(f2bf(v.x), f2bf(v.y), f2bf(v.z), f2bf(v.w));
    } else {
      int j = i - X4 - 4 * W4;     // 0..767
      int which = j >> 8;
      int o = j & 255;
      const float* src = which == 0 ? bq : which == 1 ? bk : bv;
      ((float4*)bqkv)[which * 256 + o] = ((const float4*)src)[o];
    }
  }
}

// ---------------- GEMM: C[M,N] = A[M,K] @ B[N,K]^T + bias (m97 structure, proven) ------
template<int OUT_BF16>
__global__ __launch_bounds__(256, 2)
void gemm_bt_kernel(const u16* __restrict__ A, const u16* __restrict__ B,
                    const float* __restrict__ bias, void* __restrict__ C,
                    int M, int N, int K, int scale_cols, float scale_val) {
  __shared__ u16 As[128 * 32];
  __shared__ u16 Bs[128 * 32];
  const int tid = threadIdx.x;
  const int l = tid & 63;
  const int w = tid >> 6;
  const int bm = blockIdx.y, bn = blockIdx.x;
  const int wm = w >> 1, wn = w & 1;

  f32x4 acc[4][4] = {};

  const int srow = w * 32 + (l >> 2);
  const int scol = (l & 3) * 8;
  const u16* gA0 = A + (size_t)(bm * 128 + srow) * K + scol;
  const u16* gA1 = gA0 + (size_t)16 * K;
  const u16* gB0 = B + (size_t)(bn * 128 + srow) * K + scol;
  const u16* gB1 = gB0 + (size_t)16 * K;
  u16* lA0 = As + w * 1024;
  u16* lA1 = As + w * 1024 + 512;
  u16* lB0 = Bs + w * 1024;
  u16* lB1 = Bs + w * 1024 + 512;

  const int ar = wm * 64 + (l & 15);
  const int br = wn * 64 + (l & 15);
  const int kb = (l >> 4) * 8;

  for (int k0 = 0; k0 < K; k0 += 32) {
    __syncthreads();
    gload_lds16(gA0 + k0, lA0);
    gload_lds16(gA1 + k0, lA1);
    gload_lds16(gB0 + k0, lB0);
    gload_lds16(gB1 + k0, lB1);
    __syncthreads();
    bf16x8 af[4], bfr[4];
#pragma unroll
    for (int mf = 0; mf < 4; ++mf)
      af[mf] = *(const bf16x8*)&As[(ar + mf * 16) * 32 + kb];
#pragma unroll
    for (int nf = 0; nf < 4; ++nf)
      bfr[nf] = *(const bf16x8*)&Bs[(br + nf * 16) * 32 + kb];
#pragma unroll
    for (int mf = 0; mf < 4; ++mf)
#pragma unroll
      for (int nf = 0; nf < 4; ++nf)
        acc[mf][nf] = __builtin_amdgcn_mfma_f32_16x16x32_bf16(af[mf], bfr[nf], acc[mf][nf], 0, 0, 0);
  }

  const int rbase = bm * 128 + wm * 64 + (l >> 4) * 4;
  const int cbase = bn * 128 + wn * 64 + (l & 15);
#pragma unroll
  for (int nf = 0; nf < 4; ++nf) {
    int col = cbase + nf * 16;
    float bsv = bias[col];
    float sc = (col < scale_cols) ? scale_val : 1.0f;
#pragma unroll
    for (int mf = 0; mf < 4; ++mf) {
#pragma unroll
      for (int j = 0; j < 4; ++j) {
        int row = rbase + mf * 16 + j;
        float v = (acc[mf][nf][j] + bsv) * sc;
        if (OUT_BF16) ((u16*)C)[(size_t)row * N + col] = f2bf(v);
        else          ((float*)C)[(size_t)row * N + col] = v;
      }
    }
  }
}

// softmax + P->bf16 A-frag build for one group: exp2 in place, lane-local rowsum,
// cvt_pk pairs + single symmetric cross-half exchange (lane c <-> c+32).
DEVI void softmax_pa(f32x16& sA, f32x16& sB, bf16x8* pa, float& lsum, int hi) {
  float rs = 0.f;
#pragma unroll
  for (int r = 0; r < 16; ++r) { sA[r] = __builtin_amdgcn_exp2f(sA[r]); rs += sA[r]; }
#pragma unroll
  for (int r = 0; r < 16; ++r) { sB[r] = __builtin_amdgcn_exp2f(sB[r]); rs += sB[r]; }
  lsum += rs + __shfl_xor(rs, 32, 64);
#pragma unroll
  for (int i = 0; i < 4; ++i) {
    float p0 = (8 * i + 0 < 16) ? sA[(8 * i + 0) & 15] : sB[(8 * i + 0) & 15];
    float p1 = (8 * i + 1 < 16) ? sA[(8 * i + 1) & 15] : sB[(8 * i + 1) & 15];
    float p2 = (8 * i + 2 < 16) ? sA[(8 * i + 2) & 15] : sB[(8 * i + 2) & 15];
    float p3 = (8 * i + 3 < 16) ? sA[(8 * i + 3) & 15] : sB[(8 * i + 3) & 15];
    float p4 = (8 * i + 4 < 16) ? sA[(8 * i + 4) & 15] : sB[(8 * i + 4) & 15];
    float p5 = (8 * i + 5 < 16) ? sA[(8 * i + 5) & 15] : sB[(8 * i + 5) & 15];
    float p6 = (8 * i + 6 < 16) ? sA[(8 * i + 6) & 15] : sB[(8 * i + 6) & 15];
    float p7 = (8 * i + 7 < 16) ? sA[(8 * i + 7) & 15] : sB[(8 * i + 7) & 15];
    unsigned a0, a1, b0, b1;
    asm("v_cvt_pk_bf16_f32 %0, %1, %2" : "=v"(a0) : "v"(p0), "v"(p1));
    asm("v_cvt_pk_bf16_f32 %0, %1, %2" : "=v"(a1) : "v"(p2), "v"(p3));
    asm("v_cvt_pk_bf16_f32 %0, %1, %2" : "=v"(b0) : "v"(p4), "v"(p5));
    asm("v_cvt_pk_bf16_f32 %0, %1, %2" : "=v"(b1) : "v"(p6), "v"(p7));
    unsigned t0 = hi ? a0 : b0;   // each lane sends the pair its partner needs
    unsigned t1 = hi ? a1 : b1;
    unsigned x0 = (unsigned)__shfl_xor((int)t0, 32, 64);
    unsigned x1 = (unsigned)__shfl_xor((int)t1, 32, 64);
    union { unsigned u[4]; bf16x8 v; } U;
    U.u[0] = hi ? x0 : a0;   // keys base+0,1
    U.u[1] = hi ? x1 : a1;   // keys base+2,3
    U.u[2] = hi ? b0 : x0;   // keys base+4,5
    U.u[3] = hi ? b1 : x1;   // keys base+6,7
    pa[i] = U.v;
  }
}

// ---------------- flash attention: R7-proven body + block-level split-K ----------------
// blockIdx.z = key-half (kh); each block: 4 waves x 64 q-rows x 1024 keys (16 tiles).
// Max-free exp2 softmax => partials additive. Stores RAW bf16 partial O (no normalize)
// + f32 lsum; attn_merge_kernel combines. Grid 1024 blocks -> 4 waves/SIMD resident.
__global__ __launch_bounds__(256, 2)
void attn_kernel(const u16* __restrict__ QKV, u16* __restrict__ P0, u16* __restrict__ P1,
                 float* __restrict__ Ls) {
  __shared__ u16 Ks[2][4096];  // [buf][64 key][64 d], blk-swizzled: phys = db ^ (key&7)
  __shared__ u16 Vs[2][4096];  // [buf] subtiled [key>>2][d>>4][key&3][d&15] for tr_b16

  const int tid = threadIdx.x;
  const int l = tid & 63, w = tid >> 6;
  const int hi = l >> 5, c = l & 31;
  const int bh = blockIdx.y, b = bh >> 4, h = bh & 15;
  const int kh = blockIdx.z;
  const int qb = blockIdx.x * 256 + w * 64;   // 64 q-rows per wave
  const size_t rowbase = (size_t)b * 2048;
  const int krow0 = kh << 10;                 // this block's key-range base

  // --- Q fragments for both groups
  bf16x8 qf0[4], qf1[4];
  {
    const u16* Qp0 = QKV + (rowbase + qb + c) * 3072 + h * 64 + hi * 8;
    const u16* Qp1 = QKV + (rowbase + qb + 32 + c) * 3072 + h * 64 + hi * 8;
#pragma unroll
    for (int kk = 0; kk < 4; ++kk) {
      qf0[kk] = *(const bf16x8*)(Qp0 + kk * 16);
      qf1[kk] = *(const bf16x8*)(Qp1 + kk * 16);
    }
  }

  // --- staging sources (2 K-instr + 2 V-instr per wave; lane-linear LDS dest)
  const int kd0 = (w * 2 + 0) * 64 + l;
  const int kd1 = (w * 2 + 1) * 64 + l;
  const int rK0 = kd0 >> 3, dbK0 = (kd0 & 7) ^ (rK0 & 7);
  const int rK1 = kd1 >> 3, dbK1 = (kd1 & 7) ^ (rK1 & 7);
  const u16* srcK0 = QKV + (rowbase + krow0 + rK0) * 3072 + 1024 + h * 64 + dbK0 * 8;
  const u16* srcK1 = QKV + (rowbase + krow0 + rK1) * 3072 + 1024 + h * 64 + dbK1 * 8;
  const int kV0 = (kd0 >> 5) * 4 + ((kd0 >> 1) & 3), dV0 = ((kd0 >> 3) & 3) * 16 + (kd0 & 1) * 8;
  const int kV1 = (kd1 >> 5) * 4 + ((kd1 >> 1) & 3), dV1 = ((kd1 >> 3) & 3) * 16 + (kd1 & 1) * 8;
  const u16* srcV0 = QKV + (rowbase + krow0 + kV0) * 3072 + 2048 + h * 64 + dV0;
  const u16* srcV1 = QKV + (rowbase + krow0 + kV1) * 3072 + 2048 + h * 64 + dV1;

#define STAGE(buf, tile) { \
    const size_t koff = (size_t)(tile) * 64 * 3072; \
    gload_lds16(srcK0 + koff, &Ks[buf][(w * 2 + 0) * 512]); \
    gload_lds16(srcK1 + koff, &Ks[buf][(w * 2 + 1) * 512]); \
    gload_lds16(srcV0 + koff, &Vs[buf][(w * 2 + 0) * 512]); \
    gload_lds16(srcV1 + koff, &Vs[buf][(w * 2 + 1) * 512]); \
  }

  int koffs[4];
#pragma unroll
  for (int kk = 0; kk < 4; ++kk) koffs[kk] = (((kk * 2 + hi) ^ (c & 7)) * 8);
  const int kbase = c * 64;

  const unsigned vbase = ldsaddr(&Vs[0][0]) + (unsigned)(hi * 1024 + (c >> 4) * 128 + (c & 15) * 8);

  f32x16 o00 = {0,0,0,0,0,0,0,0,0,0,0,0,0,0,0,0};
  f32x16 o01 = {0,0,0,0,0,0,0,0,0,0,0,0,0,0,0,0};
  f32x16 o10 = {0,0,0,0,0,0,0,0,0,0,0,0,0,0,0,0};
  f32x16 o11 = {0,0,0,0,0,0,0,0,0,0,0,0,0,0,0,0};
  float lsum0 = 0.f, lsum1 = 0.f;

  STAGE(0, 0);
  __syncthreads();

  for (int t = 0; t < 16; ++t) {
    const int cur = t & 1;
    if (t < 15) STAGE(cur ^ 1, t + 1);   // prefetch in flight across this tile's compute

    const u16* kp = &Ks[cur][0];
    bf16x8 kf[2][4];
#pragma unroll
    for (int kb = 0; kb < 2; ++kb)
#pragma unroll
      for (int kk = 0; kk < 4; ++kk)
        kf[kb][kk] = *(const bf16x8*)&kp[kbase + kb * 2048 + koffs[kk]];

    f32x16 sA0 = {0,0,0,0,0,0,0,0,0,0,0,0,0,0,0,0};
    f32x16 sB0 = {0,0,0,0,0,0,0,0,0,0,0,0,0,0,0,0};
    f32x16 sA1 = {0,0,0,0,0,0,0,0,0,0,0,0,0,0,0,0};
    f32x16 sB1 = {0,0,0,0,0,0,0,0,0,0,0,0,0,0,0,0};
#pragma unroll
    for (int kk = 0; kk < 4; ++kk) {
      sA0 = __builtin_amdgcn_mfma_f32_32x32x16_bf16(kf[0][kk], qf0[kk], sA0, 0, 0, 0);
      sB0 = __builtin_amdgcn_mfma_f32_32x32x16_bf16(kf[1][kk], qf0[kk], sB0, 0, 0, 0);
      sA1 = __builtin_amdgcn_mfma_f32_32x32x16_bf16(kf[0][kk], qf1[kk], sA1, 0, 0, 0);
      sB1 = __builtin_amdgcn_mfma_f32_32x32x16_bf16(kf[1][kk], qf1[kk], sB1, 0, 0, 0);
    }

    const unsigned va = vbase + (unsigned)(cur * 8192);
    u32x2 tt[4][4];
#pragma unroll
    for (int ks = 0; ks < 4; ++ks) {
      unsigned va_ks = va + (unsigned)(ks * 2048);
      asm volatile("ds_read_b64_tr_b16 %0, %1 offset:0"   : "=v"(tt[ks][0]) : "v"(va_ks));
      asm volatile("ds_read_b64_tr_b16 %0, %1 offset:512" : "=v"(tt[ks][1]) : "v"(va_ks));
      asm volatile("ds_read_b64_tr_b16 %0, %1 offset:256" : "=v"(tt[ks][2]) : "v"(va_ks));
      asm volatile("ds_read_b64_tr_b16 %0, %1 offset:768" : "=v"(tt[ks][3]) : "v"(va_ks));
    }

    bf16x8 pa0[4];
    softmax_pa(sA0, sB0, pa0, lsum0, hi);

    asm volatile("s_waitcnt lgkmcnt(0)" ::: "memory");
    __builtin_amdgcn_sched_barrier(0);   // rule 18: keep MFMA below the wait

#pragma unroll
    for (int ks = 0; ks < 4; ++ks) {
      union { u32x2 d2[2]; bf16x8 v; } V0, V1;
      V0.d2[0] = tt[ks][0]; V0.d2[1] = tt[ks][1];
      V1.d2[0] = tt[ks][2]; V1.d2[1] = tt[ks][3];
      o00 = __builtin_amdgcn_mfma_f32_32x32x16_bf16(pa0[ks], V0.v, o00, 0, 0, 0);
      o01 = __builtin_amdgcn_mfma_f32_32x32x16_bf16(pa0[ks], V1.v, o01, 0, 0, 0);
    }

    bf16x8 pa1[4];
    softmax_pa(sA1, sB1, pa1, lsum1, hi);

#pragma unroll
    for (int ks = 0; ks < 4; ++ks) {
      union { u32x2 d2[2]; bf16x8 v; } V0, V1;
      V0.d2[0] = tt[ks][0]; V0.d2[1] = tt[ks][1];
      V1.d2[0] = tt[ks][2]; V1.d2[1] = tt[ks][3];
      o10 = __builtin_amdgcn_mfma_f32_32x32x16_bf16(pa1[ks], V0.v, o10, 0, 0, 0);
      o11 = __builtin_amdgcn_mfma_f32_32x32x16_bf16(pa1[ks], V1.v, o11, 0, 0, 0);
    }

    __syncthreads();  // drains vmcnt (staging) + lgkm; next tile ready, cur free
  }

  // ---- epilogue: store RAW partials (no normalize, no shfl) + lsum
  u16* Pp = kh ? P1 : P0;
  u16* Op0 = Pp + (rowbase + qb) * 1024 + h * 64 + c;
  u16* Op1 = Pp + (rowbase + qb + 32) * 1024 + h * 64 + c;
#pragma unroll
  for (int r = 0; r < 16; ++r) {
    int q = (r & 3) + 8 * (r >> 2) + 4 * hi;
    Op0[(size_t)q * 1024]      = f2bf(o00[r]);
    Op0[(size_t)q * 1024 + 32] = f2bf(o01[r]);
    Op1[(size_t)q * 1024]      = f2bf(o10[r]);
    Op1[(size_t)q * 1024 + 32] = f2bf(o11[r]);
  }
  if (!hi) {
    float* Lp = Ls + (size_t)(kh * 64 + bh) * 2048;
    Lp[qb + c]      = lsum0;   // lane c holds full (half-range) sum for query qb+c
    Lp[qb + 32 + c] = lsum1;
  }
#undef STAGE
}

// ---------------- merge: Oa = (P0 + P1) / (l0 + l1), in-place over P1 ------------------
__global__ void attn_merge_kernel(const u16* __restrict__ P0, u16* __restrict__ P1,
                                  const float* __restrict__ Ls) {
  int i = blockIdx.x * blockDim.x + threadIdx.x;   // 1,048,576 threads, 8 u16 each
  int row = i >> 7;                                // [0, 8192)
  int chunk = i & 127;
  int h = chunk >> 3;                              // head
  int s = row & 2047;
  int bh = (row >> 11) * 16 + h;
  float l0 = Ls[(size_t)bh * 2048 + s];
  float l1 = Ls[(size_t)(64 + bh) * 2048 + s];
  float inv = 1.0f / (l0 + l1);
  const ushort4* a4 = (const ushort4*)(P0 + (size_t)i * 8);
  ushort4* b4 = (ushort4*)(P1 + (size_t)i * 8);
  ushort4 a0 = a4[0], a1 = a4[1];
  ushort4 b0 = b4[0], b1 = b4[1];
  b4[0] = make_ushort4(f2bf((bf2f(a0.x) + bf2f(b0.x)) * inv),
                       f2bf((bf2f(a0.y) + bf2f(b0.y)) * inv),
                       f2bf((bf2f(a0.z) + bf2f(b0.z)) * inv),
                       f2bf((bf2f(a0.w) + bf2f(b0.w)) * inv));
  b4[1] = make_ushort4(f2bf((bf2f(a1.x) + bf2f(b1.x)) * inv),
                       f2bf((bf2f(a1.y) + bf2f(b1.y)) * inv),
                       f2bf((bf2f(a1.z) + bf2f(b1.z)) * inv),
                       f2bf((bf2f(a1.w) + bf2f(b1.w)) * inv));
}

extern "C" void kernel_launch(void* const* d_in, const int* in_sizes, int n_in,
                              void* d_out, int out_size, void* d_ws, size_t ws_size,
                              hipStream_t stream) {
  const float* x  = (const float*)d_in[0];
  const float* Wq = (const float*)d_in[1];
  const float* bq = (const float*)d_in[2];
  const float* Wk = (const float*)d_in[3];
  const float* bk = (const float*)d_in[4];
  const float* Wv = (const float*)d_in[5];
  const float* bv = (const float*)d_in[6];
  const float* Wo = (const float*)d_in[7];
  const float* bo = (const float*)d_in[8];
  float* out = (float*)d_out;

  char* ws = (char*)d_ws;
  u16*   xb    = (u16*)(ws);                  // 8192x1024 bf16; reused as P0 post-GEMM
  u16*   Wqkvb = (u16*)(ws + 16777216);       // 3072x1024 bf16; reused as Ls post-GEMM
  u16*   Wob   = (u16*)(ws + 23068672);       // 1024x1024 bf16
  float* bqkv  = (float*)(ws + 25165824);     // 3072 fp32
  u16*   QKV   = (u16*)(ws + 25178112);       // 8192x3072 bf16
  u16*   Oa    = (u16*)(ws + 75509760);       // 8192x1024 bf16; P1, merged in-place

  u16*   P0 = xb;                              // dead after QKV GEMM
  float* Ls = (float*)(ws + 16777216);         // 2*64*2048 f32 = 1 MB, dead Wqkvb region
  u16*   P1 = Oa;

  cvt_all_kernel<<<2048, 256, 0, stream>>>(x, Wq, Wk, Wv, Wo, bq, bk, bv,
                                           xb, Wqkvb, Wob, bqkv);

  // QKV = x @ [Wq;Wk;Wv]^T + bias; Q cols scaled by log2e/8 (exp2-domain scores)
  gemm_bt_kernel<1><<<dim3(24, 64), 256, 0, stream>>>(xb, Wqkvb, bqkv, QKV,
                                                      8192, 3072, 1024, 1024,
                                                      0.125f * 1.4426950408889634f);
  // flash attention, split-K across blocks (z = key half): 1024 blocks -> 4 waves/SIMD
  attn_kernel<<<dim3(8, 64, 2), 256, 0, stream>>>(QKV, P0, P1, Ls);
  // merge partials: Oa = (P0 + P1) / (l0 + l1)
  attn_merge_kernel<<<4096, 256, 0, stream>>>(P0, P1, Ls);
  // out = Oa @ Wo^T + bo
  gemm_bt_kernel<0><<<dim3(8, 64), 256, 0, stream>>>(Oa, Wob, bo, out,
                                                     8192, 1024, 1024, 0, 1.0f);
}

// Round 14
// 191.283 us; speedup vs baseline: 1.1182x; 1.0973x over previous
//
#include <hip/hip_runtime.h>
#include <hip/hip_bf16.h>
#include <stdint.h>

typedef __attribute__((ext_vector_type(8))) short bf16x8;   // 8 bf16 = 4 VGPR
typedef __attribute__((ext_vector_type(4))) float f32x4;
typedef __attribute__((ext_vector_type(16))) float f32x16;  // 32x32 MFMA C/D
typedef __attribute__((ext_vector_type(2))) unsigned int u32x2;
typedef unsigned short u16;

#define DEVI static __device__ __forceinline__

DEVI u16 f2bf(float f) {  // RNE fp32 -> bf16
  union { float f; uint32_t u; } x; x.f = f;
  uint32_t r = (x.u + 0x7FFFu + ((x.u >> 16) & 1u)) >> 16;
  return (u16)r;
}

DEVI void gload_lds16(const void* g, void* lds) {
  __builtin_amdgcn_global_load_lds(
      (const __attribute__((address_space(1))) void*)(void*)g,
      (__attribute__((address_space(3))) void*)lds, 16, 0, 0);
}

// low 32 bits of a flat shared-pointer = LDS byte offset
DEVI unsigned ldsaddr(const void* p) { return (unsigned)(uintptr_t)p; }

// ---------------- fused fp32->bf16 converts + bias copies (1 dispatch) ----------------
__global__ void cvt_all_kernel(const float* __restrict__ x,
                               const float* __restrict__ Wq, const float* __restrict__ Wk,
                               const float* __restrict__ Wv, const float* __restrict__ Wo,
                               const float* __restrict__ bq, const float* __restrict__ bk,
                               const float* __restrict__ bv,
                               u16* __restrict__ xb, u16* __restrict__ Wqkvb,
                               u16* __restrict__ Wob, float* __restrict__ bqkv) {
  const int X4 = 2097152;          // x in float4 units (8192*1024/4)
  const int W4 = 262144;           // per-W float4 units (2^18)
  const int total = X4 + 4 * W4 + 768;
  int i = blockIdx.x * blockDim.x + threadIdx.x;
  const int stride = gridDim.x * blockDim.x;
  for (; i < total; i += stride) {
    if (i < X4) {
      float4 v = ((const float4*)x)[i];
      ((ushort4*)xb)[i] = make_ushort4(f2bf(v.x), f2bf(v.y), f2bf(v.z), f2bf(v.w));
    } else if (i < X4 + 4 * W4) {
      int j = i - X4;
      int which = j >> 18;
      int o = j & (W4 - 1);
      const float* src = which == 0 ? Wq : which == 1 ? Wk : which == 2 ? Wv : Wo;
      u16* dst = (which == 3) ? Wob : (Wqkvb + (size_t)which * 1048576);
      float4 v = ((const float4*)src)[o];
      ((ushort4*)dst)[o] = make_ushort4(f2bf(v.x), f2bf(v.y), f2bf(v.z), f2bf(v.w));
    } else {
      int j = i - X4 - 4 * W4;     // 0..767
      int which = j >> 8;
      int o = j & 255;
      const float* src = which == 0 ? bq : which == 1 ? bk : bv;
      ((float4*)bqkv)[which * 256 + o] = ((const float4*)src)[o];
    }
  }
}

// ---------------- GEMM: 128x256 tile, BK=64 (2 kh-phases), counted vmcnt(6) ------------
// C[M,N] = A[M,K] @ B[N,K]^T + bias (+col scale). 8 waves (2M x 4N), wave-tile 64x64.
// LDS 96KB: [buf][A.kh0 8KB | A.kh1 8KB | B.kh0 16KB | B.kh1 16KB]; kh-region rows are
// 64B (inherently 2-way bank access = free, m136) -> linear staging, no swizzle needed.
// Schedule (T3/T4): per K-tile two phases (kk=kh); each phase: vmcnt(6); barrier;
// stage 3 loads (one kh half-tile, 2-phase lead); 8 ds_read_b128; lgkmcnt(0);
// setprio(1); 16 MFMA; setprio(0). Never drains vmcnt to 0 in the loop.
// Stage order: ...kh1(t)@P1(t-1), kh0(t+1)@P2(t-1), kh1(t+1)@P1(t), kh0(t+2)@P2(t)...
//  - P1(t) needs kh0(t) [staged @P2(t-2)]: 6 younger loads outstanding -> vmcnt(6).
//  - P2(t) needs kh1(t) [staged @P1(t-1)]: 6 younger -> vmcnt(6).
// WAR safety: every region staged at phase p had its last reads lgkm-drained by all
// waves before p's barrier. Tail: clamped source indices write never-read regions.
template<int OUT_BF16>
__global__ __launch_bounds__(512, 2)
void gemm_kh_kernel(const u16* __restrict__ A, const u16* __restrict__ B,
                    const float* __restrict__ bias, void* __restrict__ C,
                    int M, int N, int K, int scale_cols, float scale_val) {
  __shared__ u16 S[49152];   // 96KB
  const int tid = threadIdx.x;
  const int l = tid & 63;
  const int w = tid >> 6;
  const int wm = w >> 2, wn = w & 3;
  const int bn = blockIdx.x, bm = blockIdx.y;

  // staging sources: thread covers row tid>>2 (A) / j*128 + (tid>>2) (B), chunk tid&3
  const u16* sA  = A + (size_t)(bm * 128 + (tid >> 2)) * K + (tid & 3) * 8;
  const u16* sB0 = B + (size_t)(bn * 256 + (tid >> 2)) * K + (tid & 3) * 8;
  const u16* sB1 = sB0 + (size_t)128 * K;

  // u16 offsets: buf stride 24576; A: kh*4096 + tid*8; B: 8192 + kh*8192 + j*4096 + tid*8
#define QSTAGE(bufi, kh, ko) { \
    gload_lds16(sA  + (ko), &S[(bufi) * 24576 + (kh) * 4096 + tid * 8]); \
    gload_lds16(sB0 + (ko), &S[(bufi) * 24576 + 8192 + (kh) * 8192 + tid * 8]); \
    gload_lds16(sB1 + (ko), &S[(bufi) * 24576 + 8192 + (kh) * 8192 + 4096 + tid * 8]); \
  }

  // frag read offsets (u16): row*32 + (l>>4)*8 within kh region
  const int arow = (wm * 64 + (l & 15)) * 32 + (l >> 4) * 8;
  const int brow = (wn * 64 + (l & 15)) * 32 + (l >> 4) * 8;

  f32x4 acc[4][4] = {};
  const int NT = K >> 6;

  // prologue: kh0(0), kh1(0), kh0(1)  -> P1(0)'s vmcnt(6) is already uniform
  QSTAGE(0, 0, 0);
  QSTAGE(0, 1, 32);
  QSTAGE(1, 0, 64);

  for (int kt = 0; kt < NT; ++kt) {
    const int bufo = (kt & 1) * 24576;

    // ---- P1: kk = 0 (reads kh0)
    asm volatile("s_waitcnt vmcnt(6)" ::: "memory");
    __builtin_amdgcn_s_barrier();
    asm volatile("" ::: "memory");
    { int ts = (kt + 1 < NT) ? kt + 1 : NT - 1;
      QSTAGE((kt + 1) & 1, 1, ts * 64 + 32); }      // kh1(t+1)
    {
      const u16* ap = &S[bufo];
      const u16* bp = &S[bufo + 8192];
      bf16x8 af[4], bf[4];
#pragma unroll
      for (int mf = 0; mf < 4; ++mf) af[mf] = *(const bf16x8*)&ap[arow + mf * 512];
#pragma unroll
      for (int nf = 0; nf < 4; ++nf) bf[nf] = *(const bf16x8*)&bp[brow + nf * 512];
      asm volatile("s_waitcnt lgkmcnt(0)" ::: "memory");
      __builtin_amdgcn_sched_barrier(0);
      __builtin_amdgcn_s_setprio(1);
#pragma unroll
      for (int mf = 0; mf < 4; ++mf)
#pragma unroll
        for (int nf = 0; nf < 4; ++nf)
          acc[mf][nf] = __builtin_amdgcn_mfma_f32_16x16x32_bf16(af[mf], bf[nf], acc[mf][nf], 0, 0, 0);
      __builtin_amdgcn_s_setprio(0);
    }

    // ---- P2: kk = 1 (reads kh1)
    asm volatile("s_waitcnt vmcnt(6)" ::: "memory");
    __builtin_amdgcn_s_barrier();
    asm volatile("" ::: "memory");
    { int ts = (kt + 2 < NT) ? kt + 2 : NT - 1;
      QSTAGE(kt & 1, 0, ts * 64); }                 // kh0(t+2)
    {
      const u16* ap = &S[bufo + 4096];
      const u16* bp = &S[bufo + 8192 + 8192];
      bf16x8 af[4], bf[4];
#pragma unroll
      for (int mf = 0; mf < 4; ++mf) af[mf] = *(const bf16x8*)&ap[arow + mf * 512];
#pragma unroll
      for (int nf = 0; nf < 4; ++nf) bf[nf] = *(const bf16x8*)&bp[brow + nf * 512];
      asm volatile("s_waitcnt lgkmcnt(0)" ::: "memory");
      __builtin_amdgcn_sched_barrier(0);
      __builtin_amdgcn_s_setprio(1);
#pragma unroll
      for (int mf = 0; mf < 4; ++mf)
#pragma unroll
        for (int nf = 0; nf < 4; ++nf)
          acc[mf][nf] = __builtin_amdgcn_mfma_f32_16x16x32_bf16(af[mf], bf[nf], acc[mf][nf], 0, 0, 0);
      __builtin_amdgcn_s_setprio(0);
    }
    asm volatile("" ::: "memory");
  }

  // ---- epilogue (C/D layout m89-verified: col = l&15, row = (l>>4)*4 + j)
  const int rbase = bm * 128 + wm * 64 + (l >> 4) * 4;
  const int cbase = bn * 256 + wn * 64 + (l & 15);
#pragma unroll
  for (int nf = 0; nf < 4; ++nf) {
    int col = cbase + nf * 16;
    float bsv = bias[col];
    float sc = (col < scale_cols) ? scale_val : 1.0f;
#pragma unroll
    for (int mf = 0; mf < 4; ++mf) {
#pragma unroll
      for (int j = 0; j < 4; ++j) {
        int row = rbase + mf * 16 + j;
        float v = (acc[mf][nf][j] + bsv) * sc;
        if (OUT_BF16) ((u16*)C)[(size_t)row * N + col] = f2bf(v);
        else          ((float*)C)[(size_t)row * N + col] = v;
      }
    }
  }
#undef QSTAGE
}

// softmax + P->bf16 A-frag build for one group: exp2 in place, lane-local rowsum,
// cvt_pk pairs + single symmetric cross-half exchange (lane c <-> c+32).
DEVI void softmax_pa(f32x16& sA, f32x16& sB, bf16x8* pa, float& lsum, int hi) {
  float rs = 0.f;
#pragma unroll
  for (int r = 0; r < 16; ++r) { sA[r] = __builtin_amdgcn_exp2f(sA[r]); rs += sA[r]; }
#pragma unroll
  for (int r = 0; r < 16; ++r) { sB[r] = __builtin_amdgcn_exp2f(sB[r]); rs += sB[r]; }
  lsum += rs + __shfl_xor(rs, 32, 64);
#pragma unroll
  for (int i = 0; i < 4; ++i) {
    float p0 = (8 * i + 0 < 16) ? sA[(8 * i + 0) & 15] : sB[(8 * i + 0) & 15];
    float p1 = (8 * i + 1 < 16) ? sA[(8 * i + 1) & 15] : sB[(8 * i + 1) & 15];
    float p2 = (8 * i + 2 < 16) ? sA[(8 * i + 2) & 15] : sB[(8 * i + 2) & 15];
    float p3 = (8 * i + 3 < 16) ? sA[(8 * i + 3) & 15] : sB[(8 * i + 3) & 15];
    float p4 = (8 * i + 4 < 16) ? sA[(8 * i + 4) & 15] : sB[(8 * i + 4) & 15];
    float p5 = (8 * i + 5 < 16) ? sA[(8 * i + 5) & 15] : sB[(8 * i + 5) & 15];
    float p6 = (8 * i + 6 < 16) ? sA[(8 * i + 6) & 15] : sB[(8 * i + 6) & 15];
    float p7 = (8 * i + 7 < 16) ? sA[(8 * i + 7) & 15] : sB[(8 * i + 7) & 15];
    unsigned a0, a1, b0, b1;
    asm("v_cvt_pk_bf16_f32 %0, %1, %2" : "=v"(a0) : "v"(p0), "v"(p1));
    asm("v_cvt_pk_bf16_f32 %0, %1, %2" : "=v"(a1) : "v"(p2), "v"(p3));
    asm("v_cvt_pk_bf16_f32 %0, %1, %2" : "=v"(b0) : "v"(p4), "v"(p5));
    asm("v_cvt_pk_bf16_f32 %0, %1, %2" : "=v"(b1) : "v"(p6), "v"(p7));
    unsigned t0 = hi ? a0 : b0;   // each lane sends the pair its partner needs
    unsigned t1 = hi ? a1 : b1;
    unsigned x0 = (unsigned)__shfl_xor((int)t0, 32, 64);
    unsigned x1 = (unsigned)__shfl_xor((int)t1, 32, 64);
    union { unsigned u[4]; bf16x8 v; } U;
    U.u[0] = hi ? x0 : a0;   // keys base+0,1
    U.u[1] = hi ? x1 : a1;   // keys base+2,3
    U.u[2] = hi ? b0 : x0;   // keys base+4,5
    U.u[3] = hi ? b1 : x1;   // keys base+6,7
    pa[i] = U.v;
  }
}

// ---------------- flash attention (R8 exact — best measured: 92.6 us) ------------------
// Swapped-QK^T 32x32, max-free, 64 q-rows/wave, depth-2 counted prefetch, 3 buffers.
__global__ __launch_bounds__(256, 2)
void attn_kernel(const u16* __restrict__ QKV, u16* __restrict__ O) {
  __shared__ u16 Ks[3][4096];  // [buf][64 key][64 d], blk-swizzled: phys = db ^ (key&7)
  __shared__ u16 Vs[3][4096];  // [buf] subtiled [key>>2][d>>4][key&3][d&15] for tr_b16

  const int tid = threadIdx.x;
  const int l = tid & 63, w = tid >> 6;
  const int hi = l >> 5, c = l & 31;
  const int bh = blockIdx.y, b = bh >> 4, h = bh & 15;
  const int qb = blockIdx.x * 256 + w * 64;   // 64 q-rows per wave
  const size_t rowbase = (size_t)b * 2048;

  bf16x8 qf0[4], qf1[4];
  {
    const u16* Qp0 = QKV + (rowbase + qb + c) * 3072 + h * 64 + hi * 8;
    const u16* Qp1 = QKV + (rowbase + qb + 32 + c) * 3072 + h * 64 + hi * 8;
#pragma unroll
    for (int kk = 0; kk < 4; ++kk) {
      qf0[kk] = *(const bf16x8*)(Qp0 + kk * 16);
      qf1[kk] = *(const bf16x8*)(Qp1 + kk * 16);
    }
  }

  const int kd0 = (w * 2 + 0) * 64 + l;
  const int kd1 = (w * 2 + 1) * 64 + l;
  const int rK0 = kd0 >> 3, dbK0 = (kd0 & 7) ^ (rK0 & 7);
  const int rK1 = kd1 >> 3, dbK1 = (kd1 & 7) ^ (rK1 & 7);
  const u16* srcK0 = QKV + (rowbase + rK0) * 3072 + 1024 + h * 64 + dbK0 * 8;
  const u16* srcK1 = QKV + (rowbase + rK1) * 3072 + 1024 + h * 64 + dbK1 * 8;
  const int kV0 = (kd0 >> 5) * 4 + ((kd0 >> 1) & 3), dV0 = ((kd0 >> 3) & 3) * 16 + (kd0 & 1) * 8;
  const int kV1 = (kd1 >> 5) * 4 + ((kd1 >> 1) & 3), dV1 = ((kd1 >> 3) & 3) * 16 + (kd1 & 1) * 8;
  const u16* srcV0 = QKV + (rowbase + kV0) * 3072 + 2048 + h * 64 + dV0;
  const u16* srcV1 = QKV + (rowbase + kV1) * 3072 + 2048 + h * 64 + dV1;

#define STAGE(buf, tile) { \
    const size_t koff = (size_t)(tile) * 64 * 3072; \
    gload_lds16(srcK0 + koff, &Ks[buf][(w * 2 + 0) * 512]); \
    gload_lds16(srcK1 + koff, &Ks[buf][(w * 2 + 1) * 512]); \
    gload_lds16(srcV0 + koff, &Vs[buf][(w * 2 + 0) * 512]); \
    gload_lds16(srcV1 + koff, &Vs[buf][(w * 2 + 1) * 512]); \
  }

  int koffs[4];
#pragma unroll
  for (int kk = 0; kk < 4; ++kk) koffs[kk] = (((kk * 2 + hi) ^ (c & 7)) * 8);
  const int kbase = c * 64;

  const unsigned vbase = ldsaddr(&Vs[0][0]) + (unsigned)(hi * 1024 + (c >> 4) * 128 + (c & 15) * 8);

  f32x16 o00 = {0,0,0,0,0,0,0,0,0,0,0,0,0,0,0,0};
  f32x16 o01 = {0,0,0,0,0,0,0,0,0,0,0,0,0,0,0,0};
  f32x16 o10 = {0,0,0,0,0,0,0,0,0,0,0,0,0,0,0,0};
  f32x16 o11 = {0,0,0,0,0,0,0,0,0,0,0,0,0,0,0,0};
  float lsum0 = 0.f, lsum1 = 0.f;

  STAGE(0, 0);
  STAGE(1, 1);

  int cur = 0;
  for (int t = 0; t < 32; ++t) {
    if (t < 31) { asm volatile("s_waitcnt vmcnt(4)" ::: "memory"); }
    else        { asm volatile("s_waitcnt vmcnt(0)" ::: "memory"); }
    __builtin_amdgcn_s_barrier();
    asm volatile("" ::: "memory");

    if (t < 30) {
      int bs = cur + 2; if (bs >= 3) bs -= 3;
      STAGE(bs, t + 2);
    }

    const u16* kp = &Ks[cur][0];
    bf16x8 kf[2][4];
#pragma unroll
    for (int kb = 0; kb < 2; ++kb)
#pragma unroll
      for (int kk = 0; kk < 4; ++kk)
        kf[kb][kk] = *(const bf16x8*)&kp[kbase + kb * 2048 + koffs[kk]];

    f32x16 sA0 = {0,0,0,0,0,0,0,0,0,0,0,0,0,0,0,0};
    f32x16 sB0 = {0,0,0,0,0,0,0,0,0,0,0,0,0,0,0,0};
    f32x16 sA1 = {0,0,0,0,0,0,0,0,0,0,0,0,0,0,0,0};
    f32x16 sB1 = {0,0,0,0,0,0,0,0,0,0,0,0,0,0,0,0};
#pragma unroll
    for (int kk = 0; kk < 4; ++kk) {
      sA0 = __builtin_amdgcn_mfma_f32_32x32x16_bf16(kf[0][kk], qf0[kk], sA0, 0, 0, 0);
      sB0 = __builtin_amdgcn_mfma_f32_32x32x16_bf16(kf[1][kk], qf0[kk], sB0, 0, 0, 0);
      sA1 = __builtin_amdgcn_mfma_f32_32x32x16_bf16(kf[0][kk], qf1[kk], sA1, 0, 0, 0);
      sB1 = __builtin_amdgcn_mfma_f32_32x32x16_bf16(kf[1][kk], qf1[kk], sB1, 0, 0, 0);
    }

    const unsigned va = vbase + (unsigned)(cur * 8192);
    u32x2 tt[4][4];
#pragma unroll
    for (int ks = 0; ks < 4; ++ks) {
      unsigned va_ks = va + (unsigned)(ks * 2048);
      asm volatile("ds_read_b64_tr_b16 %0, %1 offset:0"   : "=v"(tt[ks][0]) : "v"(va_ks));
      asm volatile("ds_read_b64_tr_b16 %0, %1 offset:512" : "=v"(tt[ks][1]) : "v"(va_ks));
      asm volatile("ds_read_b64_tr_b16 %0, %1 offset:256" : "=v"(tt[ks][2]) : "v"(va_ks));
      asm volatile("ds_read_b64_tr_b16 %0, %1 offset:768" : "=v"(tt[ks][3]) : "v"(va_ks));
    }

    bf16x8 pa0[4];
    softmax_pa(sA0, sB0, pa0, lsum0, hi);

    asm volatile("s_waitcnt lgkmcnt(0)" ::: "memory");
    __builtin_amdgcn_sched_barrier(0);   // rule 18: keep MFMA below the wait

#pragma unroll
    for (int ks = 0; ks < 4; ++ks) {
      union { u32x2 d2[2]; bf16x8 v; } V0, V1;
      V0.d2[0] = tt[ks][0]; V0.d2[1] = tt[ks][1];
      V1.d2[0] = tt[ks][2]; V1.d2[1] = tt[ks][3];
      o00 = __builtin_amdgcn_mfma_f32_32x32x16_bf16(pa0[ks], V0.v, o00, 0, 0, 0);
      o01 = __builtin_amdgcn_mfma_f32_32x32x16_bf16(pa0[ks], V1.v, o01, 0, 0, 0);
    }

    bf16x8 pa1[4];
    softmax_pa(sA1, sB1, pa1, lsum1, hi);

#pragma unroll
    for (int ks = 0; ks < 4; ++ks) {
      union { u32x2 d2[2]; bf16x8 v; } V0, V1;
      V0.d2[0] = tt[ks][0]; V0.d2[1] = tt[ks][1];
      V1.d2[0] = tt[ks][2]; V1.d2[1] = tt[ks][3];
      o10 = __builtin_amdgcn_mfma_f32_32x32x16_bf16(pa1[ks], V0.v, o10, 0, 0, 0);
      o11 = __builtin_amdgcn_mfma_f32_32x32x16_bf16(pa1[ks], V1.v, o11, 0, 0, 0);
    }

    asm volatile("" ::: "memory");
    cur = (cur == 2) ? 0 : cur + 1;
  }

  u16* Op0 = O + (rowbase + qb) * 1024 + h * 64 + c;
  u16* Op1 = O + (rowbase + qb + 32) * 1024 + h * 64 + c;
#pragma unroll
  for (int r = 0; r < 16; ++r) {
    int q = (r & 3) + 8 * (r >> 2) + 4 * hi;
    float inv0 = 1.0f / __shfl(lsum0, q, 64);
    float inv1 = 1.0f / __shfl(lsum1, q, 64);
    Op0[(size_t)q * 1024]      = f2bf(o00[r] * inv0);
    Op0[(size_t)q * 1024 + 32] = f2bf(o01[r] * inv0);
    Op1[(size_t)q * 1024]      = f2bf(o10[r] * inv1);
    Op1[(size_t)q * 1024 + 32] = f2bf(o11[r] * inv1);
  }
#undef STAGE
}

extern "C" void kernel_launch(void* const* d_in, const int* in_sizes, int n_in,
                              void* d_out, int out_size, void* d_ws, size_t ws_size,
                              hipStream_t stream) {
  const float* x  = (const float*)d_in[0];
  const float* Wq = (const float*)d_in[1];
  const float* bq = (const float*)d_in[2];
  const float* Wk = (const float*)d_in[3];
  const float* bk = (const float*)d_in[4];
  const float* Wv = (const float*)d_in[5];
  const float* bv = (const float*)d_in[6];
  const float* Wo = (const float*)d_in[7];
  const float* bo = (const float*)d_in[8];
  float* out = (float*)d_out;

  char* ws = (char*)d_ws;
  u16*   xb    = (u16*)(ws);                  // 8192x1024 bf16
  u16*   Wqkvb = (u16*)(ws + 16777216);       // 3072x1024 bf16
  u16*   Wob   = (u16*)(ws + 23068672);       // 1024x1024 bf16
  float* bqkv  = (float*)(ws + 25165824);     // 3072 fp32
  u16*   QKV   = (u16*)(ws + 25178112);       // 8192x3072 bf16
  u16*   Oa    = (u16*)(ws + 75509760);       // 8192x1024 bf16

  cvt_all_kernel<<<2048, 256, 0, stream>>>(x, Wq, Wk, Wv, Wo, bq, bk, bv,
                                           xb, Wqkvb, Wob, bqkv);

  // QKV = x @ [Wq;Wk;Wv]^T + bias; Q cols scaled by log2e/8 (exp2-domain scores)
  // grid 12x64 = 768 blocks = 3 exact CU rounds
  gemm_kh_kernel<1><<<dim3(12, 64), 512, 0, stream>>>(xb, Wqkvb, bqkv, QKV,
                                                      8192, 3072, 1024, 1024,
                                                      0.125f * 1.4426950408889634f);
  // flash attention (R8 exact)
  attn_kernel<<<dim3(8, 64), 256, 0, stream>>>(QKV, Oa);
  // out = Oa @ Wo^T + bo ; grid 4x64 = 256 blocks = 1 exact CU round
  gemm_kh_kernel<0><<<dim3(4, 64), 512, 0, stream>>>(Oa, Wob, bo, out,
                                                     8192, 1024, 1024, 0, 1.0f);
}

// Round 15
// 185.614 us; speedup vs baseline: 1.1524x; 1.0305x over previous
//
#include <hip/hip_runtime.h>
#include <hip/hip_bf16.h>
#include <stdint.h>

typedef __attribute__((ext_vector_type(8))) short bf16x8;   // 8 bf16 = 4 VGPR
typedef __attribute__((ext_vector_type(4))) float f32x4;
typedef __attribute__((ext_vector_type(16))) float f32x16;  // 32x32 MFMA C/D
typedef __attribute__((ext_vector_type(2))) unsigned int u32x2;
typedef unsigned short u16;

#define DEVI static __device__ __forceinline__

DEVI u16 f2bf(float f) {  // RNE fp32 -> bf16
  union { float f; uint32_t u; } x; x.f = f;
  uint32_t r = (x.u + 0x7FFFu + ((x.u >> 16) & 1u)) >> 16;
  return (u16)r;
}

DEVI void gload_lds16(const void* g, void* lds) {
  __builtin_amdgcn_global_load_lds(
      (const __attribute__((address_space(1))) void*)(void*)g,
      (__attribute__((address_space(3))) void*)lds, 16, 0, 0);
}

// low 32 bits of a flat shared-pointer = LDS byte offset
DEVI unsigned ldsaddr(const void* p) { return (unsigned)(uintptr_t)p; }

// ---------------- fused fp32->bf16 converts + bias copies (1 dispatch) ----------------
__global__ void cvt_all_kernel(const float* __restrict__ x,
                               const float* __restrict__ Wq, const float* __restrict__ Wk,
                               const float* __restrict__ Wv, const float* __restrict__ Wo,
                               const float* __restrict__ bq, const float* __restrict__ bk,
                               const float* __restrict__ bv,
                               u16* __restrict__ xb, u16* __restrict__ Wqkvb,
                               u16* __restrict__ Wob, float* __restrict__ bqkv) {
  const int X4 = 2097152;          // x in float4 units (8192*1024/4)
  const int W4 = 262144;           // per-W float4 units (2^18)
  const int total = X4 + 4 * W4 + 768;
  int i = blockIdx.x * blockDim.x + threadIdx.x;
  const int stride = gridDim.x * blockDim.x;
  for (; i < total; i += stride) {
    if (i < X4) {
      float4 v = ((const float4*)x)[i];
      ((ushort4*)xb)[i] = make_ushort4(f2bf(v.x), f2bf(v.y), f2bf(v.z), f2bf(v.w));
    } else if (i < X4 + 4 * W4) {
      int j = i - X4;
      int which = j >> 18;
      int o = j & (W4 - 1);
      const float* src = which == 0 ? Wq : which == 1 ? Wk : which == 2 ? Wv : Wo;
      u16* dst = (which == 3) ? Wob : (Wqkvb + (size_t)which * 1048576);
      float4 v = ((const float4*)src)[o];
      ((ushort4*)dst)[o] = make_ushort4(f2bf(v.x), f2bf(v.y), f2bf(v.z), f2bf(v.w));
    } else {
      int j = i - X4 - 4 * W4;     // 0..767
      int which = j >> 8;
      int o = j & 255;
      const float* src = which == 0 ? bq : which == 1 ? bk : bv;
      ((float4*)bqkv)[which * 256 + o] = ((const float4*)src)[o];
    }
  }
}

// ---------------- GEMM: 128x256 tile, BK=64 (2 kh-phases), counted vmcnt(6) ------------
// R14 structure, UNPINNED: no lgkmcnt(0)/sched_barrier pins — GEMM frag loads are
// compiler-visible, and hipcc emits fine-grained lgkmcnt(4/3/1/0) between ds_read and
// MFMA on its own (G7/m97; m141 showed order-pinning costs ~40%). Rule 18 applies to
// inline-asm ds_reads only (attn's tr_b16), not here.
template<int OUT_BF16>
__global__ __launch_bounds__(512, 2)
void gemm_kh_kernel(const u16* __restrict__ A, const u16* __restrict__ B,
                    const float* __restrict__ bias, void* __restrict__ C,
                    int M, int N, int K, int scale_cols, float scale_val) {
  __shared__ u16 S[49152];   // 96KB
  const int tid = threadIdx.x;
  const int l = tid & 63;
  const int w = tid >> 6;
  const int wm = w >> 2, wn = w & 3;
  const int bn = blockIdx.x, bm = blockIdx.y;

  const u16* sA  = A + (size_t)(bm * 128 + (tid >> 2)) * K + (tid & 3) * 8;
  const u16* sB0 = B + (size_t)(bn * 256 + (tid >> 2)) * K + (tid & 3) * 8;
  const u16* sB1 = sB0 + (size_t)128 * K;

#define QSTAGE(bufi, kh, ko) { \
    gload_lds16(sA  + (ko), &S[(bufi) * 24576 + (kh) * 4096 + tid * 8]); \
    gload_lds16(sB0 + (ko), &S[(bufi) * 24576 + 8192 + (kh) * 8192 + tid * 8]); \
    gload_lds16(sB1 + (ko), &S[(bufi) * 24576 + 8192 + (kh) * 8192 + 4096 + tid * 8]); \
  }

  const int arow = (wm * 64 + (l & 15)) * 32 + (l >> 4) * 8;
  const int brow = (wn * 64 + (l & 15)) * 32 + (l >> 4) * 8;

  f32x4 acc[4][4] = {};
  const int NT = K >> 6;

  QSTAGE(0, 0, 0);
  QSTAGE(0, 1, 32);
  QSTAGE(1, 0, 64);

  for (int kt = 0; kt < NT; ++kt) {
    const int bufo = (kt & 1) * 24576;

    // ---- P1: kk = 0 (reads kh0)
    asm volatile("s_waitcnt vmcnt(6)" ::: "memory");
    __builtin_amdgcn_s_barrier();
    asm volatile("" ::: "memory");
    { int ts = (kt + 1 < NT) ? kt + 1 : NT - 1;
      QSTAGE((kt + 1) & 1, 1, ts * 64 + 32); }      // kh1(t+1)
    {
      const u16* ap = &S[bufo];
      const u16* bp = &S[bufo + 8192];
      bf16x8 af[4], bf[4];
#pragma unroll
      for (int mf = 0; mf < 4; ++mf) af[mf] = *(const bf16x8*)&ap[arow + mf * 512];
#pragma unroll
      for (int nf = 0; nf < 4; ++nf) bf[nf] = *(const bf16x8*)&bp[brow + nf * 512];
      __builtin_amdgcn_s_setprio(1);
#pragma unroll
      for (int mf = 0; mf < 4; ++mf)
#pragma unroll
        for (int nf = 0; nf < 4; ++nf)
          acc[mf][nf] = __builtin_amdgcn_mfma_f32_16x16x32_bf16(af[mf], bf[nf], acc[mf][nf], 0, 0, 0);
      __builtin_amdgcn_s_setprio(0);
    }

    // ---- P2: kk = 1 (reads kh1)
    asm volatile("s_waitcnt vmcnt(6)" ::: "memory");
    __builtin_amdgcn_s_barrier();
    asm volatile("" ::: "memory");
    { int ts = (kt + 2 < NT) ? kt + 2 : NT - 1;
      QSTAGE(kt & 1, 0, ts * 64); }                 // kh0(t+2)
    {
      const u16* ap = &S[bufo + 4096];
      const u16* bp = &S[bufo + 8192 + 8192];
      bf16x8 af[4], bf[4];
#pragma unroll
      for (int mf = 0; mf < 4; ++mf) af[mf] = *(const bf16x8*)&ap[arow + mf * 512];
#pragma unroll
      for (int nf = 0; nf < 4; ++nf) bf[nf] = *(const bf16x8*)&bp[brow + nf * 512];
      __builtin_amdgcn_s_setprio(1);
#pragma unroll
      for (int mf = 0; mf < 4; ++mf)
#pragma unroll
        for (int nf = 0; nf < 4; ++nf)
          acc[mf][nf] = __builtin_amdgcn_mfma_f32_16x16x32_bf16(af[mf], bf[nf], acc[mf][nf], 0, 0, 0);
      __builtin_amdgcn_s_setprio(0);
    }
    asm volatile("" ::: "memory");
  }

  // ---- epilogue (C/D layout m89-verified: col = l&15, row = (l>>4)*4 + j)
  const int rbase = bm * 128 + wm * 64 + (l >> 4) * 4;
  const int cbase = bn * 256 + wn * 64 + (l & 15);
#pragma unroll
  for (int nf = 0; nf < 4; ++nf) {
    int col = cbase + nf * 16;
    float bsv = bias[col];
    float sc = (col < scale_cols) ? scale_val : 1.0f;
#pragma unroll
    for (int mf = 0; mf < 4; ++mf) {
#pragma unroll
      for (int j = 0; j < 4; ++j) {
        int row = rbase + mf * 16 + j;
        float v = (acc[mf][nf][j] + bsv) * sc;
        if (OUT_BF16) ((u16*)C)[(size_t)row * N + col] = f2bf(v);
        else          ((float*)C)[(size_t)row * N + col] = v;
      }
    }
  }
#undef QSTAGE
}

// softmax + P->bf16 A-frag build for one group: exp2 in place, lane-local rowsum,
// cvt_pk pairs + single symmetric cross-half exchange (lane c <-> c+32).
DEVI void softmax_pa(f32x16& sA, f32x16& sB, bf16x8* pa, float& lsum, int hi) {
  float rs = 0.f;
#pragma unroll
  for (int r = 0; r < 16; ++r) { sA[r] = __builtin_amdgcn_exp2f(sA[r]); rs += sA[r]; }
#pragma unroll
  for (int r = 0; r < 16; ++r) { sB[r] = __builtin_amdgcn_exp2f(sB[r]); rs += sB[r]; }
  lsum += rs + __shfl_xor(rs, 32, 64);
#pragma unroll
  for (int i = 0; i < 4; ++i) {
    float p0 = (8 * i + 0 < 16) ? sA[(8 * i + 0) & 15] : sB[(8 * i + 0) & 15];
    float p1 = (8 * i + 1 < 16) ? sA[(8 * i + 1) & 15] : sB[(8 * i + 1) & 15];
    float p2 = (8 * i + 2 < 16) ? sA[(8 * i + 2) & 15] : sB[(8 * i + 2) & 15];
    float p3 = (8 * i + 3 < 16) ? sA[(8 * i + 3) & 15] : sB[(8 * i + 3) & 15];
    float p4 = (8 * i + 4 < 16) ? sA[(8 * i + 4) & 15] : sB[(8 * i + 4) & 15];
    float p5 = (8 * i + 5 < 16) ? sA[(8 * i + 5) & 15] : sB[(8 * i + 5) & 15];
    float p6 = (8 * i + 6 < 16) ? sA[(8 * i + 6) & 15] : sB[(8 * i + 6) & 15];
    float p7 = (8 * i + 7 < 16) ? sA[(8 * i + 7) & 15] : sB[(8 * i + 7) & 15];
    unsigned a0, a1, b0, b1;
    asm("v_cvt_pk_bf16_f32 %0, %1, %2" : "=v"(a0) : "v"(p0), "v"(p1));
    asm("v_cvt_pk_bf16_f32 %0, %1, %2" : "=v"(a1) : "v"(p2), "v"(p3));
    asm("v_cvt_pk_bf16_f32 %0, %1, %2" : "=v"(b0) : "v"(p4), "v"(p5));
    asm("v_cvt_pk_bf16_f32 %0, %1, %2" : "=v"(b1) : "v"(p6), "v"(p7));
    unsigned t0 = hi ? a0 : b0;   // each lane sends the pair its partner needs
    unsigned t1 = hi ? a1 : b1;
    unsigned x0 = (unsigned)__shfl_xor((int)t0, 32, 64);
    unsigned x1 = (unsigned)__shfl_xor((int)t1, 32, 64);
    union { unsigned u[4]; bf16x8 v; } U;
    U.u[0] = hi ? x0 : a0;   // keys base+0,1
    U.u[1] = hi ? x1 : a1;   // keys base+2,3
    U.u[2] = hi ? b0 : x0;   // keys base+4,5
    U.u[3] = hi ? b1 : x1;   // keys base+6,7
    pa[i] = U.v;
  }
}

// ---------------- flash attention (R8 exact body + XCD-aware block swizzle) ------------
// Swapped-QK^T 32x32, max-free, 64 q-rows/wave, depth-2 counted prefetch, 3 buffers.
// Swizzle: grid (8,64); default round-robin puts the 8 q-blocks sharing one (b,h)'s
// K/V on 8 DIFFERENT XCDs (XCD = lin%8 = blockIdx.x). Bijective remap co-locates all
// 8 same-KV blocks on one XCD; per-XCD KV working set = 8 x 512KB = 4MB = L2 size.
__global__ __launch_bounds__(256, 2)
void attn_kernel(const u16* __restrict__ QKV, u16* __restrict__ O) {
  __shared__ u16 Ks[3][4096];  // [buf][64 key][64 d], blk-swizzled: phys = db ^ (key&7)
  __shared__ u16 Vs[3][4096];  // [buf] subtiled [key>>2][d>>4][key&3][d&15] for tr_b16

  const int tid = threadIdx.x;
  const int l = tid & 63, w = tid >> 6;
  const int hi = l >> 5, c = l & 31;
  // XCD-aware remap (bijective on [0,512)): same bh -> same lin%8 -> same XCD
  const int lin = blockIdx.x + 8 * blockIdx.y;
  const int bx = (lin >> 3) & 7;                    // q-block index [0,8)
  const int bh = (lin & 7) * 8 + (lin >> 6);        // (b,h) index [0,64)
  const int b = bh >> 4, h = bh & 15;
  const int qb = bx * 256 + w * 64;                 // 64 q-rows per wave
  const size_t rowbase = (size_t)b * 2048;

  bf16x8 qf0[4], qf1[4];
  {
    const u16* Qp0 = QKV + (rowbase + qb + c) * 3072 + h * 64 + hi * 8;
    const u16* Qp1 = QKV + (rowbase + qb + 32 + c) * 3072 + h * 64 + hi * 8;
#pragma unroll
    for (int kk = 0; kk < 4; ++kk) {
      qf0[kk] = *(const bf16x8*)(Qp0 + kk * 16);
      qf1[kk] = *(const bf16x8*)(Qp1 + kk * 16);
    }
  }

  const int kd0 = (w * 2 + 0) * 64 + l;
  const int kd1 = (w * 2 + 1) * 64 + l;
  const int rK0 = kd0 >> 3, dbK0 = (kd0 & 7) ^ (rK0 & 7);
  const int rK1 = kd1 >> 3, dbK1 = (kd1 & 7) ^ (rK1 & 7);
  const u16* srcK0 = QKV + (rowbase + rK0) * 3072 + 1024 + h * 64 + dbK0 * 8;
  const u16* srcK1 = QKV + (rowbase + rK1) * 3072 + 1024 + h * 64 + dbK1 * 8;
  const int kV0 = (kd0 >> 5) * 4 + ((kd0 >> 1) & 3), dV0 = ((kd0 >> 3) & 3) * 16 + (kd0 & 1) * 8;
  const int kV1 = (kd1 >> 5) * 4 + ((kd1 >> 1) & 3), dV1 = ((kd1 >> 3) & 3) * 16 + (kd1 & 1) * 8;
  const u16* srcV0 = QKV + (rowbase + kV0) * 3072 + 2048 + h * 64 + dV0;
  const u16* srcV1 = QKV + (rowbase + kV1) * 3072 + 2048 + h * 64 + dV1;

#define STAGE(buf, tile) { \
    const size_t koff = (size_t)(tile) * 64 * 3072; \
    gload_lds16(srcK0 + koff, &Ks[buf][(w * 2 + 0) * 512]); \
    gload_lds16(srcK1 + koff, &Ks[buf][(w * 2 + 1) * 512]); \
    gload_lds16(srcV0 + koff, &Vs[buf][(w * 2 + 0) * 512]); \
    gload_lds16(srcV1 + koff, &Vs[buf][(w * 2 + 1) * 512]); \
  }

  int koffs[4];
#pragma unroll
  for (int kk = 0; kk < 4; ++kk) koffs[kk] = (((kk * 2 + hi) ^ (c & 7)) * 8);
  const int kbase = c * 64;

  const unsigned vbase = ldsaddr(&Vs[0][0]) + (unsigned)(hi * 1024 + (c >> 4) * 128 + (c & 15) * 8);

  f32x16 o00 = {0,0,0,0,0,0,0,0,0,0,0,0,0,0,0,0};
  f32x16 o01 = {0,0,0,0,0,0,0,0,0,0,0,0,0,0,0,0};
  f32x16 o10 = {0,0,0,0,0,0,0,0,0,0,0,0,0,0,0,0};
  f32x16 o11 = {0,0,0,0,0,0,0,0,0,0,0,0,0,0,0,0};
  float lsum0 = 0.f, lsum1 = 0.f;

  STAGE(0, 0);
  STAGE(1, 1);

  int cur = 0;
  for (int t = 0; t < 32; ++t) {
    if (t < 31) { asm volatile("s_waitcnt vmcnt(4)" ::: "memory"); }
    else        { asm volatile("s_waitcnt vmcnt(0)" ::: "memory"); }
    __builtin_amdgcn_s_barrier();
    asm volatile("" ::: "memory");

    if (t < 30) {
      int bs = cur + 2; if (bs >= 3) bs -= 3;
      STAGE(bs, t + 2);
    }

    const u16* kp = &Ks[cur][0];
    bf16x8 kf[2][4];
#pragma unroll
    for (int kb = 0; kb < 2; ++kb)
#pragma unroll
      for (int kk = 0; kk < 4; ++kk)
        kf[kb][kk] = *(const bf16x8*)&kp[kbase + kb * 2048 + koffs[kk]];

    f32x16 sA0 = {0,0,0,0,0,0,0,0,0,0,0,0,0,0,0,0};
    f32x16 sB0 = {0,0,0,0,0,0,0,0,0,0,0,0,0,0,0,0};
    f32x16 sA1 = {0,0,0,0,0,0,0,0,0,0,0,0,0,0,0,0};
    f32x16 sB1 = {0,0,0,0,0,0,0,0,0,0,0,0,0,0,0,0};
#pragma unroll
    for (int kk = 0; kk < 4; ++kk) {
      sA0 = __builtin_amdgcn_mfma_f32_32x32x16_bf16(kf[0][kk], qf0[kk], sA0, 0, 0, 0);
      sB0 = __builtin_amdgcn_mfma_f32_32x32x16_bf16(kf[1][kk], qf0[kk], sB0, 0, 0, 0);
      sA1 = __builtin_amdgcn_mfma_f32_32x32x16_bf16(kf[0][kk], qf1[kk], sA1, 0, 0, 0);
      sB1 = __builtin_amdgcn_mfma_f32_32x32x16_bf16(kf[1][kk], qf1[kk], sB1, 0, 0, 0);
    }

    const unsigned va = vbase + (unsigned)(cur * 8192);
    u32x2 tt[4][4];
#pragma unroll
    for (int ks = 0; ks < 4; ++ks) {
      unsigned va_ks = va + (unsigned)(ks * 2048);
      asm volatile("ds_read_b64_tr_b16 %0, %1 offset:0"   : "=v"(tt[ks][0]) : "v"(va_ks));
      asm volatile("ds_read_b64_tr_b16 %0, %1 offset:512" : "=v"(tt[ks][1]) : "v"(va_ks));
      asm volatile("ds_read_b64_tr_b16 %0, %1 offset:256" : "=v"(tt[ks][2]) : "v"(va_ks));
      asm volatile("ds_read_b64_tr_b16 %0, %1 offset:768" : "=v"(tt[ks][3]) : "v"(va_ks));
    }

    bf16x8 pa0[4];
    softmax_pa(sA0, sB0, pa0, lsum0, hi);

    asm volatile("s_waitcnt lgkmcnt(0)" ::: "memory");
    __builtin_amdgcn_sched_barrier(0);   // rule 18: inline-asm tr_b16 reads need the pin

#pragma unroll
    for (int ks = 0; ks < 4; ++ks) {
      union { u32x2 d2[2]; bf16x8 v; } V0, V1;
      V0.d2[0] = tt[ks][0]; V0.d2[1] = tt[ks][1];
      V1.d2[0] = tt[ks][2]; V1.d2[1] = tt[ks][3];
      o00 = __builtin_amdgcn_mfma_f32_32x32x16_bf16(pa0[ks], V0.v, o00, 0, 0, 0);
      o01 = __builtin_amdgcn_mfma_f32_32x32x16_bf16(pa0[ks], V1.v, o01, 0, 0, 0);
    }

    bf16x8 pa1[4];
    softmax_pa(sA1, sB1, pa1, lsum1, hi);

#pragma unroll
    for (int ks = 0; ks < 4; ++ks) {
      union { u32x2 d2[2]; bf16x8 v; } V0, V1;
      V0.d2[0] = tt[ks][0]; V0.d2[1] = tt[ks][1];
      V1.d2[0] = tt[ks][2]; V1.d2[1] = tt[ks][3];
      o10 = __builtin_amdgcn_mfma_f32_32x32x16_bf16(pa1[ks], V0.v, o10, 0, 0, 0);
      o11 = __builtin_amdgcn_mfma_f32_32x32x16_bf16(pa1[ks], V1.v, o11, 0, 0, 0);
    }

    asm volatile("" ::: "memory");
    cur = (cur == 2) ? 0 : cur + 1;
  }

  u16* Op0 = O + (rowbase + qb) * 1024 + h * 64 + c;
  u16* Op1 = O + (rowbase + qb + 32) * 1024 + h * 64 + c;
#pragma unroll
  for (int r = 0; r < 16; ++r) {
    int q = (r & 3) + 8 * (r >> 2) + 4 * hi;
    float inv0 = 1.0f / __shfl(lsum0, q, 64);
    float inv1 = 1.0f / __shfl(lsum1, q, 64);
    Op0[(size_t)q * 1024]      = f2bf(o00[r] * inv0);
    Op0[(size_t)q * 1024 + 32] = f2bf(o01[r] * inv0);
    Op1[(size_t)q * 1024]      = f2bf(o10[r] * inv1);
    Op1[(size_t)q * 1024 + 32] = f2bf(o11[r] * inv1);
  }
#undef STAGE
}

extern "C" void kernel_launch(void* const* d_in, const int* in_sizes, int n_in,
                              void* d_out, int out_size, void* d_ws, size_t ws_size,
                              hipStream_t stream) {
  const float* x  = (const float*)d_in[0];
  const float* Wq = (const float*)d_in[1];
  const float* bq = (const float*)d_in[2];
  const float* Wk = (const float*)d_in[3];
  const float* bk = (const float*)d_in[4];
  const float* Wv = (const float*)d_in[5];
  const float* bv = (const float*)d_in[6];
  const float* Wo = (const float*)d_in[7];
  const float* bo = (const float*)d_in[8];
  float* out = (float*)d_out;

  char* ws = (char*)d_ws;
  u16*   xb    = (u16*)(ws);                  // 8192x1024 bf16
  u16*   Wqkvb = (u16*)(ws + 16777216);       // 3072x1024 bf16
  u16*   Wob   = (u16*)(ws + 23068672);       // 1024x1024 bf16
  float* bqkv  = (float*)(ws + 25165824);     // 3072 fp32
  u16*   QKV   = (u16*)(ws + 25178112);       // 8192x3072 bf16
  u16*   Oa    = (u16*)(ws + 75509760);       // 8192x1024 bf16

  cvt_all_kernel<<<2048, 256, 0, stream>>>(x, Wq, Wk, Wv, Wo, bq, bk, bv,
                                           xb, Wqkvb, Wob, bqkv);

  // QKV = x @ [Wq;Wk;Wv]^T + bias; Q cols scaled by log2e/8 (exp2-domain scores)
  gemm_kh_kernel<1><<<dim3(12, 64), 512, 0, stream>>>(xb, Wqkvb, bqkv, QKV,
                                                      8192, 3072, 1024, 1024,
                                                      0.125f * 1.4426950408889634f);
  // flash attention (R8 body + XCD swizzle)
  attn_kernel<<<dim3(8, 64), 256, 0, stream>>>(QKV, Oa);
  // out = Oa @ Wo^T + bo
  gemm_kh_kernel<0><<<dim3(4, 64), 512, 0, stream>>>(Oa, Wob, bo, out,
                                                     8192, 1024, 1024, 0, 1.0f);
}